// Round 15
// baseline (195.028 us; speedup 1.0000x reference)
//
#include <hip/hip_runtime.h>
#include <hip/hip_bf16.h>
#include <math.h>

#define EPSf 1e-7f
typedef unsigned short u16;
typedef __attribute__((ext_vector_type(8))) short bf16x8;
typedef __attribute__((ext_vector_type(4))) float f32x4;

__device__ __forceinline__ float bf2f(u16 u) {
  union { unsigned int i; float f; } x; x.i = ((unsigned int)u) << 16; return x.f;
}
__device__ __forceinline__ u16 f2bf(float f) {  // RNE
  union { float f; unsigned int i; } x; x.f = f;
  unsigned int r = x.i + 0x7fffu + ((x.i >> 16) & 1u);
  return (u16)(r >> 16);
}
__device__ __forceinline__ void gll16(const void* g, void* l) {
  __builtin_amdgcn_global_load_lds((__attribute__((address_space(1))) void*)(g),
                                   (__attribute__((address_space(3))) void*)(l),
                                   16, 0, 0);
}

// ---------------- prep: merged split_x (bx<6144) + split_z (bx>=6144) ---------------
// Zn must be pre-zeroed by hipMemsetAsync (split_z part atomicAdds into it).
__global__ __launch_bounds__(256) void prep(
    const float* __restrict__ xq, const float* __restrict__ xk, const float* __restrict__ xv,
    const float* __restrict__ zq, const float* __restrict__ zk, const float* __restrict__ zv,
    u16* __restrict__ Xh, u16* __restrict__ Xl,
    float* __restrict__ Xn, float* __restrict__ Vn,
    u16* __restrict__ ZhT, u16* __restrict__ ZlT, float* __restrict__ Zn) {
  __shared__ float tile[64][68];
  const int t = threadIdx.x;
  if (blockIdx.x < 6144) {
    const int gr = blockIdx.x * 2 + (t >> 7);
    const int mat = gr >> 12, row = gr & 4095;
    const float* X = (mat == 0) ? xq : (mat == 1) ? xk : xv;
    const int f4 = t & 127;
    float4 x = ((const float4*)(X + (size_t)row * 512))[f4];
    u16 h0 = f2bf(x.x), h1 = f2bf(x.y), h2 = f2bf(x.z), h3 = f2bf(x.w);
    u16 l0 = f2bf(x.x - bf2f(h0)), l1 = f2bf(x.y - bf2f(h1));
    u16 l2 = f2bf(x.z - bf2f(h2)), l3 = f2bf(x.w - bf2f(h3));
    ((ushort4*)(Xh + (size_t)gr * 512))[f4] = make_ushort4(h0, h1, h2, h3);
    ((ushort4*)(Xl + (size_t)gr * 512))[f4] = make_ushort4(l0, l1, l2, l3);
    float a = fmaf(x.x, x.x, fmaf(x.y, x.y, fmaf(x.z, x.z, x.w * x.w)));
    a += __shfl_xor(a, 1);  a += __shfl_xor(a, 2);  a += __shfl_xor(a, 4);
    a += __shfl_xor(a, 8);  a += __shfl_xor(a, 16); a += __shfl_xor(a, 32);
    if ((t & 63) == 0) tile[0][t >> 6] = a;
    __syncthreads();
    if (t == 0)   { Xn[gr] = tile[0][0] + tile[0][1]; Vn[gr] = 0.f; }
    if (t == 128) { Xn[gr] = tile[0][2] + tile[0][3]; Vn[gr] = 0.f; }
  } else {
    const int idx = blockIdx.x - 6144;
    const int mat = idx >> 6;
    const int cg = (idx >> 3) & 7, kt = idx & 7;
    const int c0 = cg * 64;
    const float* Z = (mat == 0) ? zq : (mat == 1) ? zk : zv;
    {
      int kl = t >> 2;
      const float* src = Z + (size_t)(kt * 64 + kl) * 512 + c0 + (t & 3) * 16;
      #pragma unroll
      for (int j = 0; j < 4; ++j) {
        float4 v = *(const float4*)(src + 4 * j);
        *(float4*)&tile[kl][(t & 3) * 16 + 4 * j] = v;
      }
    }
    __syncthreads();
    const int cl = t >> 2, kg4 = t & 3;
    const size_t zo = (size_t)mat * 512 * 512;
    float csum = 0.f;
    #pragma unroll
    for (int jj = 0; jj < 4; ++jj) {
      u16 hb[4], lb[4];
      #pragma unroll
      for (int qq = 0; qq < 4; ++qq) {
        float zval = tile[kg4 * 16 + jj * 4 + qq][cl];
        csum = fmaf(zval, zval, csum);
        u16 hh = f2bf(zval);
        hb[qq] = hh;
        lb[qq] = f2bf(zval - bf2f(hh));
      }
      size_t o = zo + (size_t)(c0 + cl) * 512 + kt * 64 + kg4 * 16 + jj * 4;
      *(ushort4*)(ZhT + o) = make_ushort4(hb[0], hb[1], hb[2], hb[3]);
      *(ushort4*)(ZlT + o) = make_ushort4(lb[0], lb[1], lb[2], lb[3]);
    }
    csum += __shfl_xor(csum, 1);
    csum += __shfl_xor(csum, 2);
    if (kg4 == 0) atomicAdd(&Zn[mat * 512 + c0 + cl], csum);
  }
}

// ---------------- proj_gemm: 64x128 bf16x2-split MFMA GEMM (R11 revert) --------------
__global__ __launch_bounds__(256) void proj_gemm(
    const u16* __restrict__ Xh, const u16* __restrict__ Xl,
    const u16* __restrict__ ZhT, const u16* __restrict__ ZlT,
    const float* __restrict__ Xn, const float* __restrict__ Zn,
    const float* __restrict__ rq, const float* __restrict__ rk, const float* __restrict__ rv,
    float* __restrict__ Vtmp, float* __restrict__ Vn) {
  const int m0 = blockIdx.x * 64;
  const int n0 = blockIdx.y * 128;
  const int mat = blockIdx.z;
  const size_t xoff = (size_t)mat * 4096 * 512;
  const size_t zoff = (size_t)mat * 512 * 512;
  const int t = threadIdx.x, wv = t >> 6, lane = t & 63;
  const int l15 = lane & 15, quad = lane >> 4;
  const int wm = wv >> 1, wn = wv & 1;

  __shared__ __align__(16) u16 SM[12288];
  __shared__ float lams[64], lam1s[64], wmxs[128], wmys[128], wmzs[128];

  if (t < 64) {
    float x2 = Xn[mat * 4096 + m0 + t];
    float lam = 2.f / fmaxf(1.f - x2, EPSf);
    lams[t] = lam; lam1s[t] = lam - 1.f;
  }
  if (t < 128) {
    float zn = fmaxf(sqrtf(Zn[mat * 512 + n0 + t]), EPSf);
    const float* R = (mat == 0) ? rq : (mat == 1) ? rk : rv;
    float tr = 2.f * R[n0 + t];
    float e = expf(tr), ei = 1.f / e;
    wmxs[t] = 0.5f * (e + ei) / zn;
    wmys[t] = 0.5f * (e - ei);
    wmzs[t] = 2.f * zn;
  }

  f32x4 acc[2][4];
  #pragma unroll
  for (int i = 0; i < 2; ++i)
    #pragma unroll
    for (int j = 0; j < 4; ++j) acc[i][j] = (f32x4){0.f, 0.f, 0.f, 0.f};

  const u16* gs[6];
  u16* ld[6];
  #pragma unroll
  for (int ci = 0; ci < 6; ++ci) {
    int c = wv + 4 * ci;
    const u16* arr; int row0, lo;
    if (c < 4)       { arr = Xh + xoff;  row0 = m0 + 16 * c;        lo = c * 512; }
    else if (c < 8)  { arr = Xl + xoff;  row0 = m0 + 16 * (c - 4);  lo = 2048 + (c - 4) * 512; }
    else if (c < 16) { arr = ZhT + zoff; row0 = n0 + 16 * (c - 8);  lo = 4096 + (c - 8) * 512; }
    else             { arr = ZlT + zoff; row0 = n0 + 16 * (c - 16); lo = 8192 + (c - 16) * 512; }
    gs[ci] = arr + (size_t)(row0 + (lane >> 2)) * 512 + (lane & 3) * 8;
    ld[ci] = SM + lo;
  }

  for (int k0 = 0; k0 < 512; k0 += 32) {
    __syncthreads();
    #pragma unroll
    for (int ci = 0; ci < 6; ++ci) gll16(gs[ci] + k0, ld[ci]);
    __syncthreads();
    bf16x8 ah[2], al[2], bh_[4], bl_[4];
    #pragma unroll
    for (int i = 0; i < 2; ++i) {
      int ra = wm * 32 + i * 16 + l15;
      ah[i] = *(const bf16x8*)&SM[ra * 32 + quad * 8];
      al[i] = *(const bf16x8*)&SM[2048 + ra * 32 + quad * 8];
    }
    #pragma unroll
    for (int j = 0; j < 4; ++j) {
      int rb = wn * 64 + j * 16 + l15;
      bh_[j] = *(const bf16x8*)&SM[4096 + rb * 32 + quad * 8];
      bl_[j] = *(const bf16x8*)&SM[8192 + rb * 32 + quad * 8];
    }
    #pragma unroll
    for (int i = 0; i < 2; ++i)
      #pragma unroll
      for (int j = 0; j < 4; ++j) {
        acc[i][j] = __builtin_amdgcn_mfma_f32_16x16x32_bf16(ah[i], bh_[j], acc[i][j], 0, 0, 0);
        acc[i][j] = __builtin_amdgcn_mfma_f32_16x16x32_bf16(ah[i], bl_[j], acc[i][j], 0, 0, 0);
        acc[i][j] = __builtin_amdgcn_mfma_f32_16x16x32_bf16(al[i], bh_[j], acc[i][j], 0, 0, 0);
      }
  }

  #pragma unroll
  for (int i = 0; i < 2; ++i) {
    float rsum[4] = {0.f, 0.f, 0.f, 0.f};
    #pragma unroll
    for (int j = 0; j < 4; ++j) {
      int nl = wn * 64 + j * 16 + l15;
      float wx = wmxs[nl], wy = wmys[nl], wz = wmzs[nl];
      #pragma unroll
      for (int r = 0; r < 4; ++r) {
        int ml = wm * 32 + i * 16 + quad * 4 + r;
        float tt = lams[ml] * acc[i][j][r] * wx - lam1s[ml] * wy;
        float v = wz * logf(tt + sqrtf(fmaf(tt, tt, 1.f)));
        Vtmp[xoff + (size_t)(m0 + ml) * 512 + (n0 + nl)] = v;
        rsum[r] = fmaf(v, v, rsum[r]);
      }
    }
    #pragma unroll
    for (int r = 0; r < 4; ++r) {
      rsum[r] += __shfl_xor(rsum[r], 1);
      rsum[r] += __shfl_xor(rsum[r], 2);
      rsum[r] += __shfl_xor(rsum[r], 4);
      rsum[r] += __shfl_xor(rsum[r], 8);
    }
    if (l15 == 0) {
      #pragma unroll
      for (int r = 0; r < 4; ++r)
        atomicAdd(&Vn[mat * 4096 + m0 + wm * 32 + i * 16 + quad * 4 + r], rsum[r]);
    }
  }
}

// ---------------- pack: qk path (coalesced relayout) + v path (transpose) -----------
__global__ __launch_bounds__(256) void pack(
    const float* __restrict__ Vtmp, const float* __restrict__ Vn,
    u16* __restrict__ Qh, u16* __restrict__ Kh, u16* __restrict__ VTb,
    float* __restrict__ q2a, float* __restrict__ aqa, float4* __restrict__ ksc) {
  __shared__ u16 tile[64][72];
  __shared__ float lams[64];
  const int t = threadIdx.x;
  if (blockIdx.x < 256) {
    const int mat = blockIdx.x >> 7;          // 0=Q, 1=K
    const int b   = (blockIdx.x >> 5) & 3;
    const int h   = (blockIdx.x >> 2) & 7;
    const int sq  = blockIdx.x & 3;
    const int s8 = t >> 3, d8 = t & 7;
    u16* outbase = (mat ? Kh : Qh) + (size_t)(b * 8 + h) * 65536;
    #pragma unroll
    for (int p = 0; p < 8; ++p) {
      const int s = sq * 256 + p * 32 + s8;
      const size_t gr = (size_t)mat * 4096 + b * 1024 + s;
      const float sc = 1.f / (1.f + sqrtf(1.f + Vn[gr]));
      const float* src = Vtmp + gr * 512 + h * 64 + d8 * 8;
      float4 xa = *(const float4*)src;
      float4 xb = *(const float4*)(src + 4);
      u16 u0 = f2bf(xa.x * sc), u1 = f2bf(xa.y * sc), u2 = f2bf(xa.z * sc), u3 = f2bf(xa.w * sc);
      u16 u4 = f2bf(xb.x * sc), u5 = f2bf(xb.y * sc), u6 = f2bf(xb.z * sc), u7 = f2bf(xb.w * sc);
      uint4 pkd;
      pkd.x = (unsigned)u0 | ((unsigned)u1 << 16);
      pkd.y = (unsigned)u2 | ((unsigned)u3 << 16);
      pkd.z = (unsigned)u4 | ((unsigned)u5 << 16);
      pkd.w = (unsigned)u6 | ((unsigned)u7 << 16);
      *(uint4*)(outbase + (size_t)s * 64 + d8 * 8) = pkd;   // 64 lanes -> 1KB contiguous
      float f0 = bf2f(u0), f1 = bf2f(u1), f2 = bf2f(u2), f3 = bf2f(u3);
      float f4 = bf2f(u4), f5 = bf2f(u5), f6 = bf2f(u6), f7 = bf2f(u7);
      float nrm = f0*f0 + f1*f1 + f2*f2 + f3*f3 + f4*f4 + f5*f5 + f6*f6 + f7*f7;
      nrm += __shfl_xor(nrm, 1);
      nrm += __shfl_xor(nrm, 2);
      nrm += __shfl_xor(nrm, 4);
      if (d8 == 0) {
        const size_t so = (size_t)(b * 8 + h) * 1024 + s;
        if (mat == 0) { q2a[so] = nrm; aqa[so] = 1.f / fmaxf(1.f - nrm, EPSf); }
        else {
          *(float2*)&ksc[so] = make_float2(nrm, 2.f / fmaxf(1.f - nrm, EPSf)); // .x=k2 .y=ck
        }
      }
    }
  } else {
    const int idx = blockIdx.x - 256;
    const int bh = idx >> 4, st = idx & 15;
    const int b = bh >> 3, h = bh & 7;
    {
      const int s = t >> 2, dg = t & 3;
      const size_t gr = (size_t)2 * 4096 + b * 1024 + st * 64 + s;
      const float sc = 1.f / (1.f + sqrtf(1.f + Vn[gr]));
      const float* src = Vtmp + gr * 512 + h * 64 + dg * 16;
      float nrm = 0.f;
      #pragma unroll
      for (int j = 0; j < 4; ++j) {
        float4 x = *(const float4*)(src + 4 * j);
        u16 u0 = f2bf(x.x * sc), u1 = f2bf(x.y * sc), u2 = f2bf(x.z * sc), u3 = f2bf(x.w * sc);
        *(ushort4*)&tile[s][dg * 16 + 4 * j] = make_ushort4(u0, u1, u2, u3);
        float f0 = bf2f(u0), f1 = bf2f(u1), f2 = bf2f(u2), f3 = bf2f(u3);
        nrm += f0 * f0 + f1 * f1 + f2 * f2 + f3 * f3;
      }
      nrm += __shfl_xor(nrm, 1);
      nrm += __shfl_xor(nrm, 2);
      if (dg == 0) {
        float lam = 2.f / fmaxf(1.f - nrm, EPSf);
        lams[s] = lam;
        ((float*)&ksc[(size_t)bh * 1024 + st * 64 + s])[3] = lam - 1.f;  // .w = lam_v - 1
      }
    }
    __syncthreads();
    const int d = t >> 2, sg = t & 3;
    u16 ob[16];
    #pragma unroll
    for (int j = 0; j < 16; ++j) {
      int ss = sg * 16 + j;
      ob[j] = f2bf(bf2f(tile[ss][d]) * lams[ss]);
    }
    u16* dst = VTb + ((size_t)bh * 64 + d) * 1024 + st * 64 + sg * 16;
    #pragma unroll
    for (int j = 0; j < 4; ++j)
      *(ushort4*)(dst + 4 * j) = make_ushort4(ob[4 * j], ob[4 * j + 1], ob[4 * j + 2], ob[4 * j + 3]);
  }
}

// ---------------- attn: 16-q blocks, 4-way kt-split, nums aliased over Ws ------------
// grid (32 bh, 64 qt) = 2048 blocks; LDS 12.4 KB -> high residency; (256,5) budget.
__global__ __launch_bounds__(256, 5) void attn(
    const u16* __restrict__ Qh, const u16* __restrict__ Kh, const u16* __restrict__ VTb,
    const float* __restrict__ q2a, const float* __restrict__ aqa,
    const float4* __restrict__ ksc, float* __restrict__ out) {
  const int bh = blockIdx.x;
  const int b = bh >> 3, h = bh & 7;
  const int q0 = blockIdx.y * 16;
  const int t = threadIdx.x, wv = t >> 6, lane = t & 63;
  const int l15 = lane & 15, quad = lane >> 4;
  const int kq = wv;  // kt subset: {kq, kq+4, kq+8, kq+12}

  __shared__ __align__(16) u16 WsAll[4 * 16 * 72];      // per-wave W[q][k]; aliased by
                                                        // nums[2][16][68] after the loop
  __shared__ float k2s[4][64], cks[4][64], l1s[4][64];
  __shared__ float dens[2][16];
  u16* Ws = WsAll + wv * (16 * 72);
  float* numsf = (float*)WsAll;                         // [(buf*16+q)*68 + d]

  const size_t qkoff = (size_t)bh * 65536;

  // Q fragments + per-q scalars (one 16-q row set per block), loop-invariant
  const int qrow = q0 + l15;
  const u16* qp = Qh + qkoff + (size_t)qrow * 64 + quad * 8;
  const bf16x8 qf0 = *(const bf16x8*)qp;
  const bf16x8 qf1 = *(const bf16x8*)(qp + 32);
  const float q2r = q2a[bh * 1024 + qrow];
  const float aqr = aqa[bh * 1024 + qrow];

  f32x4 num[4];
  #pragma unroll
  for (int tm = 0; tm < 4; ++tm) num[tm] = (f32x4){0.f, 0.f, 0.f, 0.f};
  float denp = 0.f;

  #pragma unroll 1   // keep rolled: bounded register pressure
  for (int i = 0; i < 4; ++i) {
    const int ktc = kq + 4 * i;
    float4 scur = ksc[bh * 1024 + ktc * 64 + lane];
    k2s[wv][lane] = scur.x;
    cks[wv][lane] = scur.y;
    l1s[wv][lane] = scur.w;
    bf16x8 kcur[8];
    #pragma unroll
    for (int tn = 0; tn < 4; ++tn)
      #pragma unroll
      for (int ks = 0; ks < 2; ++ks)
        kcur[tn * 2 + ks] = *(const bf16x8*)(Kh + qkoff +
            (size_t)(ktc * 64 + tn * 16 + l15) * 64 + ks * 32 + quad * 8);

    // phase A + weight chain, per k-subtile (D rows = k, cols = q)
    #pragma unroll
    for (int tn = 0; tn < 4; ++tn) {
      const float4 k2v = *(const float4*)&k2s[wv][tn * 16 + quad * 4];
      const float4 ckv = *(const float4*)&cks[wv][tn * 16 + quad * 4];
      const float4 l1v = *(const float4*)&l1s[wv][tn * 16 + quad * 4];
      f32x4 s = (f32x4){0.f, 0.f, 0.f, 0.f};
      s = __builtin_amdgcn_mfma_f32_16x16x32_bf16(kcur[tn * 2 + 0], qf0, s, 0, 0, 0);
      s = __builtin_amdgcn_mfma_f32_16x16x32_bf16(kcur[tn * 2 + 1], qf1, s, 0, 0, 0);
      unsigned up[2];
      #pragma unroll
      for (int pr = 0; pr < 2; ++pr) {
        float w2[2];
        #pragma unroll
        for (int e = 0; e < 2; ++e) {
          const int r = pr * 2 + e;
          float d2 = fmaxf(fmaf(-2.f, s[r], q2r + ((const float*)&k2v)[r]), 0.f);
          float u = fmaxf(d2 * ((const float*)&ckv)[r] * aqr, EPSf);
          w2[e] = (1.f + u) - sqrtf(fmaf(u, u, u + u));
        }
        union { __hip_bfloat162 h2; unsigned u; } cv;
        cv.h2 = __float22bfloat162_rn(make_float2(w2[0], w2[1]));
        up[pr] = cv.u;
        float wlo = __uint_as_float(cv.u << 16);
        float whi = __uint_as_float(cv.u & 0xffff0000u);
        denp = fmaf(wlo, ((const float*)&l1v)[pr * 2 + 0], denp);
        denp = fmaf(whi, ((const float*)&l1v)[pr * 2 + 1], denp);
      }
      *(uint2*)&Ws[l15 * 72 + tn * 16 + quad * 4] = make_uint2(up[0], up[1]);
    }
    // phase B: num[d][q] += V^T W^T; V fragments loaded per-ks (8 live regs)
    #pragma unroll
    for (int ks = 0; ks < 2; ++ks) {
      bf16x8 vfk[4];
      #pragma unroll
      for (int tm = 0; tm < 4; ++tm)
        vfk[tm] = *(const bf16x8*)(VTb + qkoff +
            (size_t)(tm * 16 + l15) * 1024 + ktc * 64 + ks * 32 + quad * 8);
      const bf16x8 wf = *(const bf16x8*)&Ws[l15 * 72 + ks * 32 + quad * 8];
      #pragma unroll
      for (int tm = 0; tm < 4; ++tm)
        num[tm] = __builtin_amdgcn_mfma_f32_16x16x32_bf16(vfk[tm], wf, num[tm], 0, 0, 0);
    }
  }

  // quad-reduce den partial (sum over this thread's k subset across quads)
  denp += __shfl_xor(denp, 16);
  denp += __shfl_xor(denp, 32);

  __syncthreads();   // all waves done reading Ws -> safe to alias as nums

  // 4-way kt tree-combine: waves 1,3 publish; waves 0,2 absorb; wave 2 publishes; wave 0 final
  if (wv & 1) {
    const int buf = wv >> 1;
    #pragma unroll
    for (int tm = 0; tm < 4; ++tm)
      *(float4*)&numsf[(buf * 16 + l15) * 68 + tm * 16 + quad * 4] =
          make_float4(num[tm][0], num[tm][1], num[tm][2], num[tm][3]);
    if (quad == 0) dens[buf][l15] = denp;
  }
  __syncthreads();
  if (!(wv & 1)) {
    const int buf = wv >> 1;
    #pragma unroll
    for (int tm = 0; tm < 4; ++tm) {
      float4 o = *(const float4*)&numsf[(buf * 16 + l15) * 68 + tm * 16 + quad * 4];
      num[tm][0] += o.x; num[tm][1] += o.y; num[tm][2] += o.z; num[tm][3] += o.w;
    }
    denp += dens[buf][l15];
  }
  if (wv == 2) {
    #pragma unroll
    for (int tm = 0; tm < 4; ++tm)
      *(float4*)&numsf[(16 + l15) * 68 + tm * 16 + quad * 4] =
          make_float4(num[tm][0], num[tm][1], num[tm][2], num[tm][3]);
    if (quad == 0) dens[1][l15] = denp;
  }
  __syncthreads();
  if (wv == 0) {
    #pragma unroll
    for (int tm = 0; tm < 4; ++tm) {
      float4 o = *(const float4*)&numsf[(16 + l15) * 68 + tm * 16 + quad * 4];
      num[tm][0] += o.x; num[tm][1] += o.y; num[tm][2] += o.z; num[tm][3] += o.w;
    }
    float den = denp + dens[1][l15];
    den = (fabsf(den) < EPSf) ? EPSf : den;
    float inv = 1.f / den;
    float mv[4][4];
    float p = 0.f;
    #pragma unroll
    for (int tm = 0; tm < 4; ++tm) {
      mv[tm][0] = num[tm][0] * inv;
      mv[tm][1] = num[tm][1] * inv;
      mv[tm][2] = num[tm][2] * inv;
      mv[tm][3] = num[tm][3] * inv;
      p = fmaf(mv[tm][0], mv[tm][0], p); p = fmaf(mv[tm][1], mv[tm][1], p);
      p = fmaf(mv[tm][2], mv[tm][2], p); p = fmaf(mv[tm][3], mv[tm][3], p);
    }
    p += __shfl_xor(p, 16);
    p += __shfl_xor(p, 32);
    float mn = sqrtf(p);
    float mnc = fmaxf(mn, EPSf);
    float tt2 = fminf(mnc, 1.f - 1e-6f);
    float scale = tt2 / ((1.f + sqrtf(fmaxf(1.f - tt2 * tt2, 0.f))) * mnc);
    const size_t qg = (size_t)b * 1024 + q0 + l15;
    #pragma unroll
    for (int tm = 0; tm < 4; ++tm) {
      float4 o = make_float4(mv[tm][0] * scale, mv[tm][1] * scale,
                             mv[tm][2] * scale, mv[tm][3] * scale);
      *(float4*)(out + qg * 512 + h * 64 + tm * 16 + quad * 4) = o;
    }
  }
}

// ---------------- host ----------------
extern "C" void kernel_launch(void* const* d_in, const int* in_sizes, int n_in,
                              void* d_out, int out_size, void* d_ws, size_t ws_size,
                              hipStream_t stream) {
  (void)in_sizes; (void)n_in; (void)out_size; (void)ws_size;
  const float* q  = (const float*)d_in[0];
  const float* k  = (const float*)d_in[1];
  const float* v  = (const float*)d_in[2];
  const float* zq = (const float*)d_in[3];
  const float* rq = (const float*)d_in[4];
  const float* zk = (const float*)d_in[5];
  const float* rk = (const float*)d_in[6];
  const float* zv = (const float*)d_in[7];
  const float* rv = (const float*)d_in[8];

  unsigned char* ws = (unsigned char*)d_ws;
  // phase-1 region:
  u16*   Xh   = (u16*)(ws + 0);          // 12582912
  u16*   Xl   = (u16*)(ws + 12582912);   // 12582912
  u16*   ZhT  = (u16*)(ws + 25165824);   // 1572864
  u16*   ZlT  = (u16*)(ws + 26738688);   // 1572864
  float* Vtmp = (float*)(ws + 28311552); // 25165824
  float* Xn   = (float*)(ws + 53477376); // 49152
  float* Vn   = (float*)(ws + 53526528); // 49152
  float* Zn   = (float*)(ws + 53575680); // 6144
  // phase-2 packed arrays overlay the dead Xh/Xl region (proj_gemm done):
  u16*   Qh   = (u16*)(ws + 0);          // 4194304
  u16*   Kh   = (u16*)(ws + 4194304);    // 4194304
  u16*   VTb  = (u16*)(ws + 8388608);    // 4194304
  float* q2a  = (float*)(ws + 12582912); // 131072
  float* aqa  = (float*)(ws + 12713984); // 131072
  float4* ksc = (float4*)(ws + 12845056);// 524288

  hipMemsetAsync(Zn, 0, 6144, stream);
  prep<<<6336, 256, 0, stream>>>(q, k, v, zq, zk, zv, Xh, Xl, Xn, Vn, ZhT, ZlT, Zn);
  proj_gemm<<<dim3(64, 4, 3), 256, 0, stream>>>(Xh, Xl, ZhT, ZlT, Xn, Zn, rq, rk, rv, Vtmp, Vn);
  pack<<<768, 256, 0, stream>>>(Vtmp, Vn, Qh, Kh, VTb, q2a, aqa, ksc);
  attn<<<dim3(32, 64), 256, 0, stream>>>(Qh, Kh, VTb, q2a, aqa, ksc, (float*)d_out);
}

// Round 16
// 171.043 us; speedup vs baseline: 1.1402x; 1.1402x over previous
//
#include <hip/hip_runtime.h>
#include <hip/hip_bf16.h>
#include <math.h>

#define EPSf 1e-7f
typedef unsigned short u16;
typedef __attribute__((ext_vector_type(8))) short bf16x8;
typedef __attribute__((ext_vector_type(4))) float f32x4;

__device__ __forceinline__ float bf2f(u16 u) {
  union { unsigned int i; float f; } x; x.i = ((unsigned int)u) << 16; return x.f;
}
__device__ __forceinline__ u16 f2bf(float f) {  // RNE
  union { float f; unsigned int i; } x; x.f = f;
  unsigned int r = x.i + 0x7fffu + ((x.i >> 16) & 1u);
  return (u16)(r >> 16);
}
__device__ __forceinline__ void gll16(const void* g, void* l) {
  __builtin_amdgcn_global_load_lds((__attribute__((address_space(1))) void*)(g),
                                   (__attribute__((address_space(3))) void*)(l),
                                   16, 0, 0);
}

// ---------------- prep: merged split_x (bx<6144) + split_z (bx>=6144) ---------------
// split_z writes per-kt column-norm partials Znp[kt][mat*512+col] (no atomics/memset).
__global__ __launch_bounds__(256) void prep(
    const float* __restrict__ xq, const float* __restrict__ xk, const float* __restrict__ xv,
    const float* __restrict__ zq, const float* __restrict__ zk, const float* __restrict__ zv,
    u16* __restrict__ Xh, u16* __restrict__ Xl,
    float* __restrict__ Xn, float* __restrict__ Vn,
    u16* __restrict__ ZhT, u16* __restrict__ ZlT, float* __restrict__ Znp) {
  __shared__ float tile[64][68];
  const int t = threadIdx.x;
  if (blockIdx.x < 6144) {
    const int gr = blockIdx.x * 2 + (t >> 7);
    const int mat = gr >> 12, row = gr & 4095;
    const float* X = (mat == 0) ? xq : (mat == 1) ? xk : xv;
    const int f4 = t & 127;
    float4 x = ((const float4*)(X + (size_t)row * 512))[f4];
    u16 h0 = f2bf(x.x), h1 = f2bf(x.y), h2 = f2bf(x.z), h3 = f2bf(x.w);
    u16 l0 = f2bf(x.x - bf2f(h0)), l1 = f2bf(x.y - bf2f(h1));
    u16 l2 = f2bf(x.z - bf2f(h2)), l3 = f2bf(x.w - bf2f(h3));
    ((ushort4*)(Xh + (size_t)gr * 512))[f4] = make_ushort4(h0, h1, h2, h3);
    ((ushort4*)(Xl + (size_t)gr * 512))[f4] = make_ushort4(l0, l1, l2, l3);
    float a = fmaf(x.x, x.x, fmaf(x.y, x.y, fmaf(x.z, x.z, x.w * x.w)));
    a += __shfl_xor(a, 1);  a += __shfl_xor(a, 2);  a += __shfl_xor(a, 4);
    a += __shfl_xor(a, 8);  a += __shfl_xor(a, 16); a += __shfl_xor(a, 32);
    if ((t & 63) == 0) tile[0][t >> 6] = a;
    __syncthreads();
    if (t == 0)   { Xn[gr] = tile[0][0] + tile[0][1]; Vn[gr] = 0.f; }
    if (t == 128) { Xn[gr] = tile[0][2] + tile[0][3]; Vn[gr] = 0.f; }
  } else {
    const int idx = blockIdx.x - 6144;
    const int mat = idx >> 6;
    const int cg = (idx >> 3) & 7, kt = idx & 7;
    const int c0 = cg * 64;
    const float* Z = (mat == 0) ? zq : (mat == 1) ? zk : zv;
    {
      int kl = t >> 2;
      const float* src = Z + (size_t)(kt * 64 + kl) * 512 + c0 + (t & 3) * 16;
      #pragma unroll
      for (int j = 0; j < 4; ++j) {
        float4 v = *(const float4*)(src + 4 * j);
        *(float4*)&tile[kl][(t & 3) * 16 + 4 * j] = v;
      }
    }
    __syncthreads();
    const int cl = t >> 2, kg4 = t & 3;
    const size_t zo = (size_t)mat * 512 * 512;
    float csum = 0.f;
    #pragma unroll
    for (int jj = 0; jj < 4; ++jj) {
      u16 hb[4], lb[4];
      #pragma unroll
      for (int qq = 0; qq < 4; ++qq) {
        float zval = tile[kg4 * 16 + jj * 4 + qq][cl];
        csum = fmaf(zval, zval, csum);
        u16 hh = f2bf(zval);
        hb[qq] = hh;
        lb[qq] = f2bf(zval - bf2f(hh));
      }
      size_t o = zo + (size_t)(c0 + cl) * 512 + kt * 64 + kg4 * 16 + jj * 4;
      *(ushort4*)(ZhT + o) = make_ushort4(hb[0], hb[1], hb[2], hb[3]);
      *(ushort4*)(ZlT + o) = make_ushort4(lb[0], lb[1], lb[2], lb[3]);
    }
    csum += __shfl_xor(csum, 1);
    csum += __shfl_xor(csum, 2);
    if (kg4 == 0) Znp[kt * 1536 + mat * 512 + c0 + cl] = csum;
  }
}

// ---------------- proj_gemm: 64x128 bf16x2-split MFMA, BK=64 -------------------------
// grid (64,4,3) = 768 blocks (3/CU); 48 KB staged / 192 MFMA per barrier pair.
__global__ void proj_gemm(
    const u16* __restrict__ Xh, const u16* __restrict__ Xl,
    const u16* __restrict__ ZhT, const u16* __restrict__ ZlT,
    const float* __restrict__ Xn, const float* __restrict__ Znp,
    const float* __restrict__ rq, const float* __restrict__ rk, const float* __restrict__ rv,
    float* __restrict__ Vtmp, float* __restrict__ Vn) {
  const int m0 = blockIdx.x * 64;
  const int n0 = blockIdx.y * 128;
  const int mat = blockIdx.z;
  const size_t xoff = (size_t)mat * 4096 * 512;
  const size_t zoff = (size_t)mat * 512 * 512;
  const int t = threadIdx.x, wv = t >> 6, lane = t & 63;
  const int l15 = lane & 15, quad = lane >> 4;
  const int wm = wv >> 1, wn = wv & 1;

  // SM (u16): Ah@0 (64x64=4096), Al@4096, Bh@8192 (128x64), Bl@16384; total 24576 u16
  __shared__ __align__(16) u16 SM[24576];
  __shared__ float lams[64], lam1s[64], wmxs[128], wmys[128], wmzs[128];

  if (t < 64) {
    float x2 = Xn[mat * 4096 + m0 + t];
    float lam = 2.f / fmaxf(1.f - x2, EPSf);
    lams[t] = lam; lam1s[t] = lam - 1.f;
  }
  if (t < 128) {
    float zs = 0.f;
    #pragma unroll
    for (int p = 0; p < 8; ++p) zs += Znp[p * 1536 + mat * 512 + n0 + t];
    float zn = fmaxf(sqrtf(zs), EPSf);
    const float* R = (mat == 0) ? rq : (mat == 1) ? rk : rv;
    float tr = 2.f * R[n0 + t];
    float e = expf(tr), ei = 1.f / e;
    wmxs[t] = 0.5f * (e + ei) / zn;
    wmys[t] = 0.5f * (e - ei);
    wmzs[t] = 2.f * zn;
  }

  f32x4 acc[2][4];
  #pragma unroll
  for (int i = 0; i < 2; ++i)
    #pragma unroll
    for (int j = 0; j < 4; ++j) acc[i][j] = (f32x4){0.f, 0.f, 0.f, 0.f};

  // staging: 48 chunks of 8 rows x 64 u16 (1 KB = one gll16); wave w takes w, w+4, ...
  const u16* gs[12];
  u16* ld[12];
  #pragma unroll
  for (int ci = 0; ci < 12; ++ci) {
    int c = wv + 4 * ci;
    const u16* arr; int row0, lo;
    if (c < 8)       { arr = Xh + xoff;  row0 = m0 + 8 * c;        lo = c * 512; }
    else if (c < 16) { arr = Xl + xoff;  row0 = m0 + 8 * (c - 8);  lo = 4096 + (c - 8) * 512; }
    else if (c < 32) { arr = ZhT + zoff; row0 = n0 + 8 * (c - 16); lo = 8192 + (c - 16) * 512; }
    else             { arr = ZlT + zoff; row0 = n0 + 8 * (c - 32); lo = 16384 + (c - 32) * 512; }
    gs[ci] = arr + (size_t)(row0 + (lane >> 3)) * 512 + (lane & 7) * 8;
    ld[ci] = SM + lo;
  }

  for (int k0 = 0; k0 < 512; k0 += 64) {
    __syncthreads();
    #pragma unroll
    for (int ci = 0; ci < 12; ++ci) gll16(gs[ci] + k0, ld[ci]);
    __syncthreads();
    #pragma unroll
    for (int ksub = 0; ksub < 2; ++ksub) {
      bf16x8 ah[2], al[2], bh_[4], bl_[4];
      #pragma unroll
      for (int i = 0; i < 2; ++i) {
        int ra = wm * 32 + i * 16 + l15;
        ah[i] = *(const bf16x8*)&SM[ra * 64 + ksub * 32 + quad * 8];
        al[i] = *(const bf16x8*)&SM[4096 + ra * 64 + ksub * 32 + quad * 8];
      }
      #pragma unroll
      for (int j = 0; j < 4; ++j) {
        int rb = wn * 64 + j * 16 + l15;
        bh_[j] = *(const bf16x8*)&SM[8192 + rb * 64 + ksub * 32 + quad * 8];
        bl_[j] = *(const bf16x8*)&SM[16384 + rb * 64 + ksub * 32 + quad * 8];
      }
      #pragma unroll
      for (int i = 0; i < 2; ++i)
        #pragma unroll
        for (int j = 0; j < 4; ++j) {
          acc[i][j] = __builtin_amdgcn_mfma_f32_16x16x32_bf16(ah[i], bh_[j], acc[i][j], 0, 0, 0);
          acc[i][j] = __builtin_amdgcn_mfma_f32_16x16x32_bf16(ah[i], bl_[j], acc[i][j], 0, 0, 0);
          acc[i][j] = __builtin_amdgcn_mfma_f32_16x16x32_bf16(al[i], bh_[j], acc[i][j], 0, 0, 0);
        }
    }
  }

  #pragma unroll
  for (int i = 0; i < 2; ++i) {
    float rsum[4] = {0.f, 0.f, 0.f, 0.f};
    #pragma unroll
    for (int j = 0; j < 4; ++j) {
      int nl = wn * 64 + j * 16 + l15;
      float wx = wmxs[nl], wy = wmys[nl], wz = wmzs[nl];
      #pragma unroll
      for (int r = 0; r < 4; ++r) {
        int ml = wm * 32 + i * 16 + quad * 4 + r;
        float tt = lams[ml] * acc[i][j][r] * wx - lam1s[ml] * wy;
        float v = wz * logf(tt + sqrtf(fmaf(tt, tt, 1.f)));
        Vtmp[xoff + (size_t)(m0 + ml) * 512 + (n0 + nl)] = v;
        rsum[r] = fmaf(v, v, rsum[r]);
      }
    }
    #pragma unroll
    for (int r = 0; r < 4; ++r) {
      rsum[r] += __shfl_xor(rsum[r], 1);
      rsum[r] += __shfl_xor(rsum[r], 2);
      rsum[r] += __shfl_xor(rsum[r], 4);
      rsum[r] += __shfl_xor(rsum[r], 8);
    }
    if (l15 == 0) {
      #pragma unroll
      for (int r = 0; r < 4; ++r)
        atomicAdd(&Vn[mat * 4096 + m0 + wm * 32 + i * 16 + quad * 4 + r], rsum[r]);
    }
  }
}

// ---------------- pack: qk path (coalesced relayout) + v path (transpose) -----------
__global__ __launch_bounds__(256) void pack(
    const float* __restrict__ Vtmp, const float* __restrict__ Vn,
    u16* __restrict__ Qh, u16* __restrict__ Kh, u16* __restrict__ VTb,
    float* __restrict__ q2a, float* __restrict__ aqa, float4* __restrict__ ksc) {
  __shared__ u16 tile[64][72];
  __shared__ float lams[64];
  const int t = threadIdx.x;
  if (blockIdx.x < 256) {
    const int mat = blockIdx.x >> 7;          // 0=Q, 1=K
    const int b   = (blockIdx.x >> 5) & 3;
    const int h   = (blockIdx.x >> 2) & 7;
    const int sq  = blockIdx.x & 3;
    const int s8 = t >> 3, d8 = t & 7;
    u16* outbase = (mat ? Kh : Qh) + (size_t)(b * 8 + h) * 65536;
    #pragma unroll
    for (int p = 0; p < 8; ++p) {
      const int s = sq * 256 + p * 32 + s8;
      const size_t gr = (size_t)mat * 4096 + b * 1024 + s;
      const float sc = 1.f / (1.f + sqrtf(1.f + Vn[gr]));
      const float* src = Vtmp + gr * 512 + h * 64 + d8 * 8;
      float4 xa = *(const float4*)src;
      float4 xb = *(const float4*)(src + 4);
      u16 u0 = f2bf(xa.x * sc), u1 = f2bf(xa.y * sc), u2 = f2bf(xa.z * sc), u3 = f2bf(xa.w * sc);
      u16 u4 = f2bf(xb.x * sc), u5 = f2bf(xb.y * sc), u6 = f2bf(xb.z * sc), u7 = f2bf(xb.w * sc);
      uint4 pkd;
      pkd.x = (unsigned)u0 | ((unsigned)u1 << 16);
      pkd.y = (unsigned)u2 | ((unsigned)u3 << 16);
      pkd.z = (unsigned)u4 | ((unsigned)u5 << 16);
      pkd.w = (unsigned)u6 | ((unsigned)u7 << 16);
      *(uint4*)(outbase + (size_t)s * 64 + d8 * 8) = pkd;   // 64 lanes -> 1KB contiguous
      float f0 = bf2f(u0), f1 = bf2f(u1), f2 = bf2f(u2), f3 = bf2f(u3);
      float f4 = bf2f(u4), f5 = bf2f(u5), f6 = bf2f(u6), f7 = bf2f(u7);
      float nrm = f0*f0 + f1*f1 + f2*f2 + f3*f3 + f4*f4 + f5*f5 + f6*f6 + f7*f7;
      nrm += __shfl_xor(nrm, 1);
      nrm += __shfl_xor(nrm, 2);
      nrm += __shfl_xor(nrm, 4);
      if (d8 == 0) {
        const size_t so = (size_t)(b * 8 + h) * 1024 + s;
        if (mat == 0) { q2a[so] = nrm; aqa[so] = 1.f / fmaxf(1.f - nrm, EPSf); }
        else {
          *(float2*)&ksc[so] = make_float2(nrm, 2.f / fmaxf(1.f - nrm, EPSf)); // .x=k2 .y=ck
        }
      }
    }
  } else {
    const int idx = blockIdx.x - 256;
    const int bh = idx >> 4, st = idx & 15;
    const int b = bh >> 3, h = bh & 7;
    {
      const int s = t >> 2, dg = t & 3;
      const size_t gr = (size_t)2 * 4096 + b * 1024 + st * 64 + s;
      const float sc = 1.f / (1.f + sqrtf(1.f + Vn[gr]));
      const float* src = Vtmp + gr * 512 + h * 64 + dg * 16;
      float nrm = 0.f;
      #pragma unroll
      for (int j = 0; j < 4; ++j) {
        float4 x = *(const float4*)(src + 4 * j);
        u16 u0 = f2bf(x.x * sc), u1 = f2bf(x.y * sc), u2 = f2bf(x.z * sc), u3 = f2bf(x.w * sc);
        *(ushort4*)&tile[s][dg * 16 + 4 * j] = make_ushort4(u0, u1, u2, u3);
        float f0 = bf2f(u0), f1 = bf2f(u1), f2 = bf2f(u2), f3 = bf2f(u3);
        nrm += f0 * f0 + f1 * f1 + f2 * f2 + f3 * f3;
      }
      nrm += __shfl_xor(nrm, 1);
      nrm += __shfl_xor(nrm, 2);
      if (dg == 0) {
        float lam = 2.f / fmaxf(1.f - nrm, EPSf);
        lams[s] = lam;
        ((float*)&ksc[(size_t)bh * 1024 + st * 64 + s])[3] = lam - 1.f;  // .w = lam_v - 1
      }
    }
    __syncthreads();
    const int d = t >> 2, sg = t & 3;
    u16 ob[16];
    #pragma unroll
    for (int j = 0; j < 16; ++j) {
      int ss = sg * 16 + j;
      ob[j] = f2bf(bf2f(tile[ss][d]) * lams[ss]);
    }
    u16* dst = VTb + ((size_t)bh * 64 + d) * 1024 + st * 64 + sg * 16;
    #pragma unroll
    for (int j = 0; j < 4; ++j)
      *(ushort4*)(dst + 4 * j) = make_ushort4(ob[4 * j], ob[4 * j + 1], ob[4 * j + 2], ob[4 * j + 3]);
  }
}

// ---------------- attn: R11 exact — 4-way kt-split, 32-q blocks, K/scalar prefetch ---
__global__ __launch_bounds__(256, 3) void attn(
    const u16* __restrict__ Qh, const u16* __restrict__ Kh, const u16* __restrict__ VTb,
    const float* __restrict__ q2a, const float* __restrict__ aqa,
    const float4* __restrict__ ksc, float* __restrict__ out) {
  const int bh = blockIdx.x;
  const int b = bh >> 3, h = bh & 7;
  const int q0 = blockIdx.y * 32;
  const int t = threadIdx.x, wv = t >> 6, lane = t & 63;
  const int l15 = lane & 15, quad = lane >> 4;
  const int kq = wv;  // kt subset: {kq, kq+4, kq+8, kq+12}

  __shared__ __align__(16) u16 Ws[4][32 * 72];          // per-wave W[q][k]
  __shared__ float k2s[4][64], cks[4][64], l1s[4][64];  // per-wave k scalars
  __shared__ __align__(16) float nums[2][32][68];       // tree-combine buffers
  __shared__ float dens[2][32];

  const size_t qkoff = (size_t)bh * 65536;

  // Q fragments (B-operand) + per-q scalars, loop-invariant
  bf16x8 qf[2][2];
  float q2r[2], aqr[2];
  #pragma unroll
  for (int qs = 0; qs < 2; ++qs) {
    int qrow = q0 + qs * 16 + l15;
    const u16* qp = Qh + qkoff + (size_t)qrow * 64 + quad * 8;
    qf[qs][0] = *(const bf16x8*)qp;
    qf[qs][1] = *(const bf16x8*)(qp + 32);
    q2r[qs] = q2a[bh * 1024 + qrow];
    aqr[qs] = aqa[bh * 1024 + qrow];
  }

  f32x4 num[2][4];
  #pragma unroll
  for (int qs = 0; qs < 2; ++qs)
    #pragma unroll
    for (int tm = 0; tm < 4; ++tm) num[qs][tm] = (f32x4){0.f, 0.f, 0.f, 0.f};
  float denp[2] = {0.f, 0.f};

  // preload kt = kq
  bf16x8 kcur[8];
  #pragma unroll
  for (int tn = 0; tn < 4; ++tn)
    #pragma unroll
    for (int ks = 0; ks < 2; ++ks)
      kcur[tn * 2 + ks] = *(const bf16x8*)(Kh + qkoff +
          (size_t)(kq * 64 + tn * 16 + l15) * 64 + ks * 32 + quad * 8);
  float4 scur = ksc[bh * 1024 + kq * 64 + lane];

  #pragma unroll 1   // keep rolled: bounded register pressure
  for (int i = 0; i < 4; ++i) {
    const int ktc = kq + 4 * i;
    const int kti = (i < 3) ? ktc + 4 : ktc;
    // prefetch next K tile + scalars (one kt ahead; independent of phase A)
    bf16x8 knxt[8];
    #pragma unroll
    for (int tn = 0; tn < 4; ++tn)
      #pragma unroll
      for (int ks = 0; ks < 2; ++ks)
        knxt[tn * 2 + ks] = *(const bf16x8*)(Kh + qkoff +
            (size_t)(kti * 64 + tn * 16 + l15) * 64 + ks * 32 + quad * 8);
    float4 snxt = ksc[bh * 1024 + kti * 64 + lane];
    // wave-private k scalars into LDS (in-wave DS ordering, no barrier)
    k2s[wv][lane] = scur.x;
    cks[wv][lane] = scur.y;
    l1s[wv][lane] = scur.w;

    // phase A + weight chain, per k-subtile
    #pragma unroll
    for (int tn = 0; tn < 4; ++tn) {
      const float4 k2v = *(const float4*)&k2s[wv][tn * 16 + quad * 4];
      const float4 ckv = *(const float4*)&cks[wv][tn * 16 + quad * 4];
      const float4 l1v = *(const float4*)&l1s[wv][tn * 16 + quad * 4];
      #pragma unroll
      for (int qs = 0; qs < 2; ++qs) {
        f32x4 s = (f32x4){0.f, 0.f, 0.f, 0.f};
        s = __builtin_amdgcn_mfma_f32_16x16x32_bf16(kcur[tn * 2 + 0], qf[qs][0], s, 0, 0, 0);
        s = __builtin_amdgcn_mfma_f32_16x16x32_bf16(kcur[tn * 2 + 1], qf[qs][1], s, 0, 0, 0);
        unsigned up[2];
        #pragma unroll
        for (int pr = 0; pr < 2; ++pr) {
          float w2[2];
          #pragma unroll
          for (int e = 0; e < 2; ++e) {
            const int r = pr * 2 + e;
            float d2 = fmaxf(fmaf(-2.f, s[r], q2r[qs] + ((const float*)&k2v)[r]), 0.f);
            float u = fmaxf(d2 * ((const float*)&ckv)[r] * aqr[qs], EPSf);
            w2[e] = (1.f + u) - sqrtf(fmaf(u, u, u + u));
          }
          union { __hip_bfloat162 h2; unsigned u; } cv;
          cv.h2 = __float22bfloat162_rn(make_float2(w2[0], w2[1]));
          up[pr] = cv.u;
          float wlo = __uint_as_float(cv.u << 16);
          float whi = __uint_as_float(cv.u & 0xffff0000u);
          denp[qs] = fmaf(wlo, ((const float*)&l1v)[pr * 2 + 0], denp[qs]);
          denp[qs] = fmaf(whi, ((const float*)&l1v)[pr * 2 + 1], denp[qs]);
        }
        *(uint2*)&Ws[wv][(qs * 16 + l15) * 72 + tn * 16 + quad * 4] = make_uint2(up[0], up[1]);
      }
    }
    // phase B: num[d][q] += V^T W^T; V fragments loaded per-ks (16 live regs)
    #pragma unroll
    for (int ks = 0; ks < 2; ++ks) {
      bf16x8 vfk[4];
      #pragma unroll
      for (int tm = 0; tm < 4; ++tm)
        vfk[tm] = *(const bf16x8*)(VTb + qkoff +
            (size_t)(tm * 16 + l15) * 1024 + ktc * 64 + ks * 32 + quad * 8);
      #pragma unroll
      for (int qs = 0; qs < 2; ++qs) {
        const bf16x8 wf = *(const bf16x8*)&Ws[wv][(qs * 16 + l15) * 72 + ks * 32 + quad * 8];
        #pragma unroll
        for (int tm = 0; tm < 4; ++tm)
          num[qs][tm] = __builtin_amdgcn_mfma_f32_16x16x32_bf16(
              vfk[tm], wf, num[qs][tm], 0, 0, 0);
      }
    }
    // rotate prefetch
    #pragma unroll
    for (int j = 0; j < 8; ++j) kcur[j] = knxt[j];
    scur = snxt;
  }

  // quad-reduce den partials
  #pragma unroll
  for (int qs = 0; qs < 2; ++qs) {
    denp[qs] += __shfl_xor(denp[qs], 16);
    denp[qs] += __shfl_xor(denp[qs], 32);
  }

  // 4-way kt tree-combine: waves 1,3 publish; waves 0,2 absorb; wave 2 publishes; wave 0 final
  if (wv & 1) {
    const int buf = wv >> 1;
    #pragma unroll
    for (int qs = 0; qs < 2; ++qs) {
      #pragma unroll
      for (int tm = 0; tm < 4; ++tm)
        *(float4*)&nums[buf][qs * 16 + l15][tm * 16 + quad * 4] =
            make_float4(num[qs][tm][0], num[qs][tm][1], num[qs][tm][2], num[qs][tm][3]);
      if (quad == 0) dens[buf][qs * 16 + l15] = denp[qs];
    }
  }
  __syncthreads();
  if (!(wv & 1)) {
    const int buf = wv >> 1;
    #pragma unroll
    for (int qs = 0; qs < 2; ++qs) {
      #pragma unroll
      for (int tm = 0; tm < 4; ++tm) {
        float4 o = *(const float4*)&nums[buf][qs * 16 + l15][tm * 16 + quad * 4];
        num[qs][tm][0] += o.x; num[qs][tm][1] += o.y;
        num[qs][tm][2] += o.z; num[qs][tm][3] += o.w;
      }
      denp[qs] += dens[buf][qs * 16 + l15];
    }
  }
  if (wv == 2) {
    #pragma unroll
    for (int qs = 0; qs < 2; ++qs) {
      #pragma unroll
      for (int tm = 0; tm < 4; ++tm)
        *(float4*)&nums[1][qs * 16 + l15][tm * 16 + quad * 4] =
            make_float4(num[qs][tm][0], num[qs][tm][1], num[qs][tm][2], num[qs][tm][3]);
      if (quad == 0) dens[1][qs * 16 + l15] = denp[qs];
    }
  }
  __syncthreads();
  if (wv == 0) {
    #pragma unroll
    for (int qs = 0; qs < 2; ++qs) {
      #pragma unroll
      for (int tm = 0; tm < 4; ++tm) {
        float4 o = *(const float4*)&nums[1][qs * 16 + l15][tm * 16 + quad * 4];
        num[qs][tm][0] += o.x; num[qs][tm][1] += o.y;
        num[qs][tm][2] += o.z; num[qs][tm][3] += o.w;
      }
      float den = denp[qs] + dens[1][qs * 16 + l15];
      den = (fabsf(den) < EPSf) ? EPSf : den;
      float inv = 1.f / den;
      float mv[4][4];
      float p = 0.f;
      #pragma unroll
      for (int tm = 0; tm < 4; ++tm) {
        mv[tm][0] = num[qs][tm][0] * inv;
        mv[tm][1] = num[qs][tm][1] * inv;
        mv[tm][2] = num[qs][tm][2] * inv;
        mv[tm][3] = num[qs][tm][3] * inv;
        p = fmaf(mv[tm][0], mv[tm][0], p); p = fmaf(mv[tm][1], mv[tm][1], p);
        p = fmaf(mv[tm][2], mv[tm][2], p); p = fmaf(mv[tm][3], mv[tm][3], p);
      }
      p += __shfl_xor(p, 16);
      p += __shfl_xor(p, 32);
      float mn = sqrtf(p);
      float mnc = fmaxf(mn, EPSf);
      float tt2 = fminf(mnc, 1.f - 1e-6f);
      float scale = tt2 / ((1.f + sqrtf(fmaxf(1.f - tt2 * tt2, 0.f))) * mnc);
      const size_t qg = (size_t)b * 1024 + q0 + qs * 16 + l15;
      #pragma unroll
      for (int tm = 0; tm < 4; ++tm) {
        float4 o = make_float4(mv[tm][0] * scale, mv[tm][1] * scale,
                               mv[tm][2] * scale, mv[tm][3] * scale);
        *(float4*)(out + qg * 512 + h * 64 + tm * 16 + quad * 4) = o;
      }
    }
  }
}

// ---------------- host ----------------
extern "C" void kernel_launch(void* const* d_in, const int* in_sizes, int n_in,
                              void* d_out, int out_size, void* d_ws, size_t ws_size,
                              hipStream_t stream) {
  (void)in_sizes; (void)n_in; (void)out_size; (void)ws_size;
  const float* q  = (const float*)d_in[0];
  const float* k  = (const float*)d_in[1];
  const float* v  = (const float*)d_in[2];
  const float* zq = (const float*)d_in[3];
  const float* rq = (const float*)d_in[4];
  const float* zk = (const float*)d_in[5];
  const float* rk = (const float*)d_in[6];
  const float* zv = (const float*)d_in[7];
  const float* rv = (const float*)d_in[8];

  unsigned char* ws = (unsigned char*)d_ws;
  // phase-1 region:
  u16*   Xh   = (u16*)(ws + 0);          // 12582912
  u16*   Xl   = (u16*)(ws + 12582912);   // 12582912
  u16*   ZhT  = (u16*)(ws + 25165824);   // 1572864
  u16*   ZlT  = (u16*)(ws + 26738688);   // 1572864
  float* Vtmp = (float*)(ws + 28311552); // 25165824
  float* Xn   = (float*)(ws + 53477376); // 49152
  float* Vn   = (float*)(ws + 53526528); // 49152
  float* Znp  = (float*)(ws + 53575680); // 8*1536*4 = 49152
  // phase-2 packed arrays overlay the dead Xh/Xl region (proj_gemm done):
  u16*   Qh   = (u16*)(ws + 0);          // 4194304
  u16*   Kh   = (u16*)(ws + 4194304);    // 4194304
  u16*   VTb  = (u16*)(ws + 8388608);    // 4194304
  float* q2a  = (float*)(ws + 12582912); // 131072
  float* aqa  = (float*)(ws + 12713984); // 131072
  float4* ksc = (float4*)(ws + 12845056);// 524288

  prep<<<6336, 256, 0, stream>>>(q, k, v, zq, zk, zv, Xh, Xl, Xn, Vn, ZhT, ZlT, Znp);
  proj_gemm<<<dim3(64, 4, 3), 256, 0, stream>>>(Xh, Xl, ZhT, ZlT, Xn, Znp, rq, rk, rv, Vtmp, Vn);
  pack<<<768, 256, 0, stream>>>(Vtmp, Vn, Qh, Kh, VTb, q2a, aqa, ksc);
  attn<<<dim3(32, 32), 256, 0, stream>>>(Qh, Kh, VTb, q2a, aqa, ksc, (float*)d_out);
}